// Round 1
// baseline (712.728 us; speedup 1.0000x reference)
//
#include <hip/hip_runtime.h>

// ---------- shapes ----------
#define BB 32
#define CIN 128
#define HH 64
#define WW 64
#define EE 384
#define EBC 128   // per-branch channels
#define HID 24
#define NPIX (HH*WW)          // 4096
#define NTOK (BB*NPIX)        // 131072

typedef __attribute__((ext_vector_type(8))) short short8;
typedef __attribute__((ext_vector_type(4))) float f32x4;
typedef __attribute__((ext_vector_type(4))) unsigned short us4;

__device__ __forceinline__ unsigned short f2bf(float f) {
    unsigned u = __float_as_uint(f);
    unsigned r = u + 0x7fffu + ((u >> 16) & 1u);
    return (unsigned short)(r >> 16);
}
__device__ __forceinline__ float bf2f(unsigned short u) {
    return __uint_as_float(((unsigned)u) << 16);
}
// monotone float -> uint mapping for atomicMax over signed floats
__device__ __forceinline__ unsigned fmapu(float f) {
    unsigned u = __float_as_uint(f);
    return (u & 0x80000000u) ? ~u : (u | 0x80000000u);
}
__device__ __forceinline__ float funmap(unsigned u) {
    unsigned b = (u & 0x80000000u) ? (u ^ 0x80000000u) : ~u;
    return __uint_as_float(b);
}

// ---------- P0a: x [B,C,H,W] f32 -> xh [B,H,W,C] bf16 (LDS transpose, coalesced) ----------
__global__ void repack_x(const float* __restrict__ x, unsigned short* __restrict__ xh) {
    int y = blockIdx.x, b = blockIdx.y;
    __shared__ unsigned short t[CIN][WW + 6];
    const float* xp = x + (((size_t)b * CIN) * HH + y) * WW;
    #pragma unroll
    for (int it = 0; it < 32; ++it) {
        int xc = threadIdx.x & 63;
        int c = (threadIdx.x >> 6) + it * 4;
        t[c][xc] = f2bf(xp[(size_t)c * NPIX + xc]);
    }
    __syncthreads();
    unsigned short* op = xh + (((size_t)b * HH + y) * WW) * CIN;
    #pragma unroll
    for (int it = 0; it < 8; ++it) {
        int id = threadIdx.x + it * 256;
        int xc = id >> 5, c0 = (id & 31) * 4;
        us4 v = { t[c0][xc], t[c0 + 1][xc], t[c0 + 2][xc], t[c0 + 3][xc] };
        *(us4*)(op + xc * CIN + c0) = v;
    }
}

// ---------- P0b: conv weights -> fragment-ordered bf16 [tap][cb][mt][lane][8ch],
//            fusion_w -> fragment-ordered bf16 [cb12][m24][lane][8ch], init pools ----------
__global__ void repack_w(const float* __restrict__ w3, const float* __restrict__ w5,
                         const float* __restrict__ w7, const float* __restrict__ fw,
                         unsigned short* __restrict__ wrep, unsigned short* __restrict__ fwb,
                         float* __restrict__ psum, unsigned* __restrict__ pmax) {
    int idx = blockIdx.x * 256 + threadIdx.x;
    if (idx < 83 * 16384) {
        int j = idx & 7;
        int lane = (idx >> 3) & 63;
        int mt = (idx >> 9) & 7;
        int cb = (idx >> 12) & 3;
        int t = idx >> 14;
        int l16 = lane & 15, g4 = lane >> 4;
        int o = mt * 16 + l16;
        int c = cb * 32 + g4 * 8 + j;
        float v;
        if (t < 9)       { int tt = t;      int dy = tt / 3, dx = tt % 3; v = w3[((o * CIN + c) * 3 + dy) * 3 + dx]; }
        else if (t < 34) { int tt = t - 9;  int dy = tt / 5, dx = tt % 5; v = w5[((o * CIN + c) * 5 + dy) * 5 + dx]; }
        else             { int tt = t - 34; int dy = tt / 7, dx = tt % 7; v = w7[((o * CIN + c) * 7 + dy) * 7 + dx]; }
        wrep[idx] = f2bf(v);
    }
    if (idx < EE * EE) {
        int j = idx & 7;
        int lane = (idx >> 3) & 63;
        int mc = idx >> 9;           // 0..287 = cb*24 + m
        int m = mc % 24, cb = mc / 24;
        int l16 = lane & 15, g4 = lane >> 4;
        int o = m * 16 + l16;
        int c = cb * 32 + g4 * 8 + j;
        fwb[idx] = f2bf(fw[o * EE + c]);
    }
    if (idx < BB * EE) { psum[idx] = 0.f; pmax[idx] = 0u; }
}

// ---------- P1: conv as implicit GEMM, LDS-staged input tile ----------
// block: (y-tile of 4 rows, batch). 4 waves, wave = 1 row x 64 px x ALL 128 out-ch.
// Full M=128 per block (no half split): input tile staged ONCE per output tile,
// A-fragments double-buffered in registers across taps so the matrix pipe never
// waits on global/L1 weight-load latency.
template <int KS>
__global__ __launch_bounds__(256, 2) void conv_mfma(
        const unsigned short* __restrict__ xh, const unsigned short* __restrict__ wrp,
        const float* __restrict__ bias, unsigned short* __restrict__ fused,
        float* __restrict__ psum, unsigned* __restrict__ pmax, int choff) {
    constexpr int PK = KS / 2;
    constexpr int RT = 4 + 2 * PK;    // tile rows
    constexpr int TPX = 64 + 2 * PK;  // tile px (with halo)
    constexpr int NCH = RT * 4 * TPX; // 16B chunks in tile
    constexpr int NT = KS * KS;       // taps

    __shared__ short8 smem[NCH];

    int b = blockIdx.z;
    int y0 = blockIdx.x * 4;
    int lane = threadIdx.x & 63, wv = threadIdx.x >> 6;
    int l16 = lane & 15, g4 = lane >> 4;

    f32x4 acc[8][4];
    #pragma unroll
    for (int i = 0; i < 8; ++i)
        #pragma unroll
        for (int j = 0; j < 4; ++j) acc[i][j] = (f32x4){0.f, 0.f, 0.f, 0.f};

    const unsigned short* xb = xh + (size_t)b * (HH * WW * CIN);
    const short8* wv8 = (const short8*)wrp;

    for (int cb = 0; cb < 4; ++cb) {
        if (cb) __syncthreads();
        for (int i = threadIdx.x; i < NCH; i += 256) {
            int g = i & 3;
            int rp = i >> 2;
            int p = rp % TPX;
            int r = rp / TPX;
            int iy = y0 + r - PK, ix = p - PK;
            short8 v = {};
            if ((unsigned)iy < (unsigned)HH && (unsigned)ix < (unsigned)WW)
                v = *(const short8*)(xb + ((iy * WW + ix) * CIN + cb * 32 + g * 8));
            smem[(r * 4 + g) * TPX + p] = v;
        }
        __syncthreads();

        // A double-buffer: prefetch tap t+1 while MFMAing tap t.
        short8 a0[8], a1[8];
        {
            const short8* wf = wv8 + ((size_t)(cb * 8)) * 64 + lane;
            #pragma unroll
            for (int mt = 0; mt < 8; ++mt) a0[mt] = wf[mt * 64];
        }
        #pragma unroll
        for (int t = 0; t < NT; ++t) {
            short8* ac = (t & 1) ? a1 : a0;   // static under full unroll
            short8* an = (t & 1) ? a0 : a1;
            if (t + 1 < NT) {
                const short8* wf = wv8 + ((size_t)(((t + 1) * 4 + cb) * 8)) * 64 + lane;
                #pragma unroll
                for (int mt = 0; mt < 8; ++mt) an[mt] = wf[mt * 64];
            }
            int dy = t / KS, dx = t % KS;
            int lrow = ((wv + dy) * 4 + g4) * TPX + l16 + dx;
            short8 bfv[4];
            #pragma unroll
            for (int nt = 0; nt < 4; ++nt) bfv[nt] = smem[lrow + nt * 16];
            #pragma unroll
            for (int nt = 0; nt < 4; ++nt)
                #pragma unroll
                for (int mt = 0; mt < 8; ++mt)
                    acc[mt][nt] = __builtin_amdgcn_mfma_f32_16x16x32_bf16(ac[mt], bfv[nt], acc[mt][nt], 0, 0, 0);
        }
    }

    // epilogue: bias, bf16 store (token layout), channel pooling
    int y = y0 + wv;
    #pragma unroll
    for (int mt = 0; mt < 8; ++mt) {
        int orow = mt * 16 + g4 * 4;  // C/D: row = g4*4 + reg
        f32x4 bv = *(const f32x4*)(bias + orow);
        float sacc[4] = {0.f, 0.f, 0.f, 0.f};
        float macc[4] = {-1e30f, -1e30f, -1e30f, -1e30f};
        #pragma unroll
        for (int nt = 0; nt < 4; ++nt) {
            int pix = y * WW + nt * 16 + l16;  // col = lane&15
            us4 pk;
            #pragma unroll
            for (int r = 0; r < 4; ++r) {
                float vv = acc[mt][nt][r] + bv[r];
                sacc[r] += vv;
                macc[r] = fmaxf(macc[r], vv);
                pk[r] = f2bf(vv);
            }
            *(us4*)(fused + ((size_t)(b * NPIX + pix)) * EE + choff + orow) = pk;
        }
        #pragma unroll
        for (int r = 0; r < 4; ++r) {
            float s = sacc[r], m = macc[r];
            #pragma unroll
            for (int sh = 1; sh < 16; sh <<= 1) {
                s += __shfl_xor(s, sh);
                m = fmaxf(m, __shfl_xor(m, sh));
            }
            if (l16 == 0) {
                atomicAdd(&psum[b * EE + choff + orow + r], s);
                atomicMax(&pmax[b * EE + choff + orow + r], fmapu(m));
            }
        }
    }
}

// ---------- P2: channel attention (W2·relu(a)+W2·relu(b) = W2·(relu(a)+relu(b))) ----------
__global__ void attn_kernel(const float* __restrict__ psum, const unsigned* __restrict__ pmax,
                            const float* __restrict__ ca_w1, const float* __restrict__ ca_w2,
                            float* __restrict__ attn) {
    int b = blockIdx.x;
    __shared__ float av[EE], mxv[EE], hsum[HID];
    int t = threadIdx.x;
    if (t < EE) {
        av[t] = psum[b * EE + t] * (1.0f / (float)NPIX);
        mxv[t] = funmap(pmax[b * EE + t]);
    }
    __syncthreads();
    if (t < HID) {
        float sa = 0.f, sm = 0.f;
        for (int c = 0; c < EE; ++c) {
            float w = ca_w1[t * EE + c];
            sa += w * av[c];
            sm += w * mxv[c];
        }
        hsum[t] = fmaxf(sa, 0.f) + fmaxf(sm, 0.f);
    }
    __syncthreads();
    if (t < EE) {
        float s = 0.f;
        for (int h = 0; h < HID; ++h) s += ca_w2[t * HID + h] * hsum[h];
        attn[b * EE + t] = 1.f / (1.f + __expf(-s));
    }
}

// ---------- P3: 1x1 fusion GEMM (attn folded into LDS-staged B) + fused LayerNorm ----------
// block: one b, 64 tokens, M=384. 4 waves split M (96 each), all 64 tokens.
#define BPITCH 392  // token pitch in LDS (chs)
__global__ __launch_bounds__(256, 2) void fuse_ln(
        const unsigned short* __restrict__ fused, const unsigned short* __restrict__ fwb,
        const float* __restrict__ attn,
        const float* __restrict__ fusion_b, const float* __restrict__ ln_g,
        const float* __restrict__ ln_b, float* __restrict__ out) {
    int b = blockIdx.y;
    int p0 = blockIdx.x * 64;
    int lane = threadIdx.x & 63, wv = threadIdx.x >> 6;
    int l16 = lane & 15, g4 = lane >> 4;

    __shared__ unsigned short sB[64 * BPITCH];
    __shared__ float sattn[EE];
    __shared__ float s_sum[4][64], s_sq[4][64], s_mean[64], s_rstd[64];

    for (int i = threadIdx.x; i < EE; i += 256) sattn[i] = attn[b * EE + i];
    __syncthreads();

    // stage 64 tokens x 384 ch, scaled by attn
    const unsigned short* fb = fused + ((size_t)(b * NPIX + p0)) * EE;
    for (int i = threadIdx.x; i < 64 * 48; i += 256) {
        int cg = i % 48, tok = i / 48;
        short8 raw = *(const short8*)(fb + tok * EE + cg * 8);
        short8 o;
        #pragma unroll
        for (int j = 0; j < 8; ++j)
            o[j] = (short)f2bf(bf2f((unsigned short)raw[j]) * sattn[cg * 8 + j]);
        *(short8*)(sB + tok * BPITCH + cg * 8) = o;
    }
    __syncthreads();

    f32x4 acc[6][4];
    #pragma unroll
    for (int i = 0; i < 6; ++i)
        #pragma unroll
        for (int j = 0; j < 4; ++j) acc[i][j] = (f32x4){0.f, 0.f, 0.f, 0.f};

    const short8* fw8 = (const short8*)fwb;
    for (int cb = 0; cb < 12; ++cb) {
        int c0 = cb * 32 + g4 * 8;
        short8 a[6];
        #pragma unroll
        for (int mt = 0; mt < 6; ++mt)
            a[mt] = fw8[(cb * 24 + wv * 6 + mt) * 64 + lane];  // lane-contiguous
        #pragma unroll
        for (int nt = 0; nt < 4; ++nt) {
            short8 bf = *(const short8*)(sB + (nt * 16 + l16) * BPITCH + c0);
            #pragma unroll
            for (int mt = 0; mt < 6; ++mt)
                acc[mt][nt] = __builtin_amdgcn_mfma_f32_16x16x32_bf16(a[mt], bf, acc[mt][nt], 0, 0, 0);
        }
    }

    // bias add + per-wave LN partials
    #pragma unroll
    for (int nt = 0; nt < 4; ++nt) {
        float ps = 0.f, pq = 0.f;
        #pragma unroll
        for (int mt = 0; mt < 6; ++mt) {
            int o = wv * 96 + mt * 16 + g4 * 4;
            f32x4 bv = *(const f32x4*)(fusion_b + o);
            #pragma unroll
            for (int r = 0; r < 4; ++r) {
                float v = acc[mt][nt][r] + bv[r];
                acc[mt][nt][r] = v;
                ps += v;
                pq += v * v;
            }
        }
        ps += __shfl_xor(ps, 16); pq += __shfl_xor(pq, 16);
        ps += __shfl_xor(ps, 32); pq += __shfl_xor(pq, 32);
        if (g4 == 0) { s_sum[wv][nt * 16 + l16] = ps; s_sq[wv][nt * 16 + l16] = pq; }
    }
    __syncthreads();
    if (threadIdx.x < 64) {
        int pix = threadIdx.x;
        float s = 0.f, q = 0.f;
        #pragma unroll
        for (int w = 0; w < 4; ++w) { s += s_sum[w][pix]; q += s_sq[w][pix]; }
        float mean = s * (1.0f / (float)EE);
        float var = q * (1.0f / (float)EE) - mean * mean;
        s_mean[pix] = mean;
        s_rstd[pix] = rsqrtf(var + 1e-5f);
    }
    __syncthreads();

    #pragma unroll
    for (int nt = 0; nt < 4; ++nt) {
        int pix = nt * 16 + l16;
        float mean = s_mean[pix], rstd = s_rstd[pix];
        size_t tokbase = ((size_t)(b * NPIX + p0 + pix)) * EE;
        #pragma unroll
        for (int mt = 0; mt < 6; ++mt) {
            int o = wv * 96 + mt * 16 + g4 * 4;
            f32x4 g = *(const f32x4*)(ln_g + o);
            f32x4 be = *(const f32x4*)(ln_b + o);
            f32x4 res;
            #pragma unroll
            for (int r = 0; r < 4; ++r)
                res[r] = (acc[mt][nt][r] - mean) * rstd * g[r] + be[r];
            *(f32x4*)(out + tokbase + o) = res;
        }
    }
}

// ---------- launch ----------
extern "C" void kernel_launch(void* const* d_in, const int* in_sizes, int n_in,
                              void* d_out, int out_size, void* d_ws, size_t ws_size,
                              hipStream_t stream) {
    const float* x    = (const float*)d_in[0];
    const float* w3   = (const float*)d_in[1];
    const float* b3   = (const float*)d_in[2];
    const float* w5   = (const float*)d_in[3];
    const float* b5   = (const float*)d_in[4];
    const float* w7   = (const float*)d_in[5];
    const float* b7   = (const float*)d_in[6];
    const float* caw1 = (const float*)d_in[7];
    const float* caw2 = (const float*)d_in[8];
    const float* fw   = (const float*)d_in[9];
    const float* fbias= (const float*)d_in[10];
    const float* lng  = (const float*)d_in[11];
    const float* lnb  = (const float*)d_in[12];
    float* out = (float*)d_out;

    char* ws = (char*)d_ws;
    size_t off = 0;
    unsigned short* xh   = (unsigned short*)(ws + off); off += (size_t)BB * HH * WW * CIN * 2;       // 33.5 MB
    unsigned short* wrep = (unsigned short*)(ws + off); off += (size_t)83 * EBC * CIN * 2;           // 2.7 MB
    unsigned short* fwb  = (unsigned short*)(ws + off); off += (size_t)EE * EE * 2;                  // 0.3 MB
    unsigned short* fused= (unsigned short*)(ws + off); off += (size_t)NTOK * EE * 2;                // 100.7 MB
    float*    psum = (float*)(ws + off);    off += (size_t)BB * EE * 4;
    unsigned* pmax = (unsigned*)(ws + off); off += (size_t)BB * EE * 4;
    float*    attn = (float*)(ws + off);    off += (size_t)BB * EE * 4;

    repack_x<<<dim3(HH, BB), 256, 0, stream>>>(x, xh);
    repack_w<<<dim3(5312), 256, 0, stream>>>(w3, w5, w7, fw, wrep, fwb, psum, pmax);

    conv_mfma<3><<<dim3(16, 1, BB), 256, 0, stream>>>(xh, wrep + 0 * 16384,  b3, fused, psum, pmax, 0);
    conv_mfma<5><<<dim3(16, 1, BB), 256, 0, stream>>>(xh, wrep + 9 * 16384,  b5, fused, psum, pmax, 128);
    conv_mfma<7><<<dim3(16, 1, BB), 256, 0, stream>>>(xh, wrep + 34 * 16384, b7, fused, psum, pmax, 256);

    attn_kernel<<<dim3(BB), 384, 0, stream>>>(psum, pmax, caw1, caw2, attn);
    fuse_ln<<<dim3(NPIX / 64, BB), 256, 0, stream>>>(fused, fwb, attn, fbias, lng, lnb, out);
}

// Round 2
// 689.219 us; speedup vs baseline: 1.0341x; 1.0341x over previous
//
#include <hip/hip_runtime.h>

// ---------- shapes ----------
#define BB 32
#define CIN 128
#define HH 64
#define WW 64
#define EE 384
#define EBC 128   // per-branch channels
#define HID 24
#define NPIX (HH*WW)          // 4096
#define NTOK (BB*NPIX)        // 131072

// padded bf16 input: [B][XH][XW][CIN], zero halo (rows +3 top, cols +3 left)
#define XW 70
#define XH 72

typedef __attribute__((ext_vector_type(8))) short short8;
typedef __attribute__((ext_vector_type(4))) float f32x4;
typedef __attribute__((ext_vector_type(4))) unsigned short us4;

__device__ __forceinline__ unsigned short f2bf(float f) {
    unsigned u = __float_as_uint(f);
    unsigned r = u + 0x7fffu + ((u >> 16) & 1u);
    return (unsigned short)(r >> 16);
}
__device__ __forceinline__ float bf2f(unsigned short u) {
    return __uint_as_float(((unsigned)u) << 16);
}
// monotone float -> uint mapping for atomicMax over signed floats
__device__ __forceinline__ unsigned fmapu(float f) {
    unsigned u = __float_as_uint(f);
    return (u & 0x80000000u) ? ~u : (u | 0x80000000u);
}
__device__ __forceinline__ float funmap(unsigned u) {
    unsigned b = (u & 0x80000000u) ? (u ^ 0x80000000u) : ~u;
    return __uint_as_float(b);
}

// ---------- P0a: x [B,C,H,W] f32 -> xh [B,XH,XW,C] bf16 padded, zero halo ----------
__global__ void repack_x(const float* __restrict__ x, unsigned short* __restrict__ xh) {
    int py = blockIdx.x, b = blockIdx.y;
    int y = py - 3;
    unsigned short* orow = xh + ((size_t)(b * XH + py)) * XW * CIN;
    if ((unsigned)y >= (unsigned)HH) {
        // zero row: 70*128 shorts = 1120 short8 chunks
        for (int i = threadIdx.x; i < XW * CIN / 8; i += 256)
            ((short8*)orow)[i] = (short8){};
        return;
    }
    __shared__ unsigned short t[CIN][WW + 6];
    const float* xp = x + (((size_t)b * CIN) * HH + y) * WW;
    #pragma unroll
    for (int it = 0; it < 32; ++it) {
        int xc = threadIdx.x & 63;
        int c = (threadIdx.x >> 6) + it * 4;
        t[c][xc] = f2bf(xp[(size_t)c * NPIX + xc]);
    }
    __syncthreads();
    unsigned short* op = orow + 3 * CIN;  // interior starts at px=3
    #pragma unroll
    for (int it = 0; it < 8; ++it) {
        int id = threadIdx.x + it * 256;
        int xc = id >> 5, c0 = (id & 31) * 4;
        us4 v = { t[c0][xc], t[c0 + 1][xc], t[c0 + 2][xc], t[c0 + 3][xc] };
        *(us4*)(op + xc * CIN + c0) = v;
    }
    // zero left/right halos: px {0,1,2,67,68,69}, 16 chunks each
    if (threadIdx.x < 96) {
        int pxsel = threadIdx.x >> 4;                // 0..5
        int px = pxsel < 3 ? pxsel : 64 + pxsel;     // 0,1,2,67,68,69
        ((short8*)(orow + px * CIN))[threadIdx.x & 15] = (short8){};
    }
}

// ---------- P0b: conv weights -> fragment-ordered bf16 [tap][cb][mt][lane][8ch],
//            fusion_w -> fragment-ordered bf16 [cb12][m24][lane][8ch], init pools ----------
__global__ void repack_w(const float* __restrict__ w3, const float* __restrict__ w5,
                         const float* __restrict__ w7, const float* __restrict__ fw,
                         unsigned short* __restrict__ wrep, unsigned short* __restrict__ fwb,
                         float* __restrict__ psum, unsigned* __restrict__ pmax) {
    int idx = blockIdx.x * 256 + threadIdx.x;
    if (idx < 83 * 16384) {
        int j = idx & 7;
        int lane = (idx >> 3) & 63;
        int mt = (idx >> 9) & 7;
        int cb = (idx >> 12) & 3;
        int t = idx >> 14;
        int l16 = lane & 15, g4 = lane >> 4;
        int o = mt * 16 + l16;
        int c = cb * 32 + g4 * 8 + j;
        float v;
        if (t < 9)       { int tt = t;      int dy = tt / 3, dx = tt % 3; v = w3[((o * CIN + c) * 3 + dy) * 3 + dx]; }
        else if (t < 34) { int tt = t - 9;  int dy = tt / 5, dx = tt % 5; v = w5[((o * CIN + c) * 5 + dy) * 5 + dx]; }
        else             { int tt = t - 34; int dy = tt / 7, dx = tt % 7; v = w7[((o * CIN + c) * 7 + dy) * 7 + dx]; }
        wrep[idx] = f2bf(v);
    }
    if (idx < EE * EE) {
        int j = idx & 7;
        int lane = (idx >> 3) & 63;
        int mc = idx >> 9;           // 0..287 = cb*24 + m
        int m = mc % 24, cb = mc / 24;
        int l16 = lane & 15, g4 = lane >> 4;
        int o = m * 16 + l16;
        int c = cb * 32 + g4 * 8 + j;
        fwb[idx] = f2bf(fw[o * EE + c]);
    }
    if (idx < BB * EE) { psum[idx] = 0.f; pmax[idx] = 0u; }
}

// ---------- P1: all three convs in ONE kernel (implicit GEMM, async-staged LDS tile) ----------
// block: (y-tile of 4 rows, branch x batch). 4 waves, wave = 1 row x 64 px x ALL 128 out-ch.
// Staging via global_load_lds (async, zero VALU bounds checks thanks to padded xh).
// A (weights) double-buffered in registers; sched_barrier(0) pins prefetch issue
// before each tap's MFMA cluster so load latency hides under the previous cluster.

#define SMEM_CHUNKS 2832   // KS=7: 10*4*70 = 2800 chunks + 32 pad for partial instr overflow

template <int KS>
__device__ __forceinline__ void conv_branch(
        const unsigned short* __restrict__ xb,     // batch base of padded xh
        const short8* __restrict__ wv8,            // fragment-ordered weights for this branch
        const float* __restrict__ bias, unsigned short* __restrict__ fused,
        float* __restrict__ psum, unsigned* __restrict__ pmax,
        int b, int y0, int choff, short8* smem) {
    constexpr int PK = KS / 2;
    constexpr int RT = 4 + 2 * PK;          // tile rows
    constexpr int TPX = 64 + 2 * PK;        // tile px (with halo)
    constexpr int NCH = RT * 4 * TPX;       // 16B chunks in tile
    constexpr int NT = KS * KS;             // taps
    constexpr int NINSTR = (NCH + 63) / 64; // global_load_lds per cb

    int lane = threadIdx.x & 63, wv = threadIdx.x >> 6;
    int l16 = lane & 15, g4 = lane >> 4;

    f32x4 acc[8][4];
    #pragma unroll
    for (int i = 0; i < 8; ++i)
        #pragma unroll
        for (int j = 0; j < 4; ++j) acc[i][j] = (f32x4){0.f, 0.f, 0.f, 0.f};

    for (int cb = 0; cb < 4; ++cb) {
        if (cb) __syncthreads();
        // async stage: each wave issues NINSTR/4 global_load_lds of 1KB each.
        // LDS chunk c = k*64+lane maps to (r,g,p); global src is per-lane.
        for (int k = wv; k < NINSTR; k += 4) {
            int c = k * 64 + lane;
            int rg = c / TPX;
            int p = c - rg * TPX;
            int r = rg >> 2;
            int g = rg & 3;
            const unsigned short* src = xb +
                ((size_t)((y0 + r - PK + 3) * XW + (p - PK + 3))) * CIN + cb * 32 + g * 8;
            short8* dst = smem + k * 64;   // wave-uniform base; HW adds lane*16
            __builtin_amdgcn_global_load_lds(
                (const __attribute__((address_space(1))) void*)src,
                (__attribute__((address_space(3))) void*)dst, 16, 0, 0);
        }
        // preload A for tap 0 (completes during staging drain)
        short8 a0[8], a1[8];
        {
            const short8* wf = wv8 + ((size_t)(cb * 8)) * 64 + lane;
            #pragma unroll
            for (int mt = 0; mt < 8; ++mt) a0[mt] = wf[mt * 64];
        }
        __syncthreads();

        #pragma unroll
        for (int t = 0; t < NT; ++t) {
            short8* ac = (t & 1) ? a1 : a0;   // static under full unroll
            short8* an = (t & 1) ? a0 : a1;
            int dy = t / KS, dx = t % KS;
            int lrow = ((wv + dy) * 4 + g4) * TPX + l16 + dx;
            short8 bfv[4];
            #pragma unroll
            for (int nt = 0; nt < 4; ++nt) bfv[nt] = smem[lrow + nt * 16];
            if (t + 1 < NT) {
                const short8* wf = wv8 + ((size_t)(((t + 1) * 4 + cb) * 8)) * 64 + lane;
                #pragma unroll
                for (int mt = 0; mt < 8; ++mt) an[mt] = wf[mt * 64];
            }
            // pin: all loads above must issue before the MFMA cluster below
            __builtin_amdgcn_sched_barrier(0);
            #pragma unroll
            for (int nt = 0; nt < 4; ++nt)
                #pragma unroll
                for (int mt = 0; mt < 8; ++mt)
                    acc[mt][nt] = __builtin_amdgcn_mfma_f32_16x16x32_bf16(ac[mt], bfv[nt], acc[mt][nt], 0, 0, 0);
        }
    }

    // epilogue: bias, bf16 store (token layout), channel pooling
    int y = y0 + wv;
    #pragma unroll
    for (int mt = 0; mt < 8; ++mt) {
        int orow = mt * 16 + g4 * 4;  // C/D: row = g4*4 + reg
        f32x4 bv = *(const f32x4*)(bias + orow);
        float sacc[4] = {0.f, 0.f, 0.f, 0.f};
        float macc[4] = {-1e30f, -1e30f, -1e30f, -1e30f};
        #pragma unroll
        for (int nt = 0; nt < 4; ++nt) {
            int pix = y * WW + nt * 16 + l16;  // col = lane&15
            us4 pk;
            #pragma unroll
            for (int r = 0; r < 4; ++r) {
                float vv = acc[mt][nt][r] + bv[r];
                sacc[r] += vv;
                macc[r] = fmaxf(macc[r], vv);
                pk[r] = f2bf(vv);
            }
            *(us4*)(fused + ((size_t)(b * NPIX + pix)) * EE + choff + orow) = pk;
        }
        #pragma unroll
        for (int r = 0; r < 4; ++r) {
            float s = sacc[r], m = macc[r];
            #pragma unroll
            for (int sh = 1; sh < 16; sh <<= 1) {
                s += __shfl_xor(s, sh);
                m = fmaxf(m, __shfl_xor(m, sh));
            }
            if (l16 == 0) {
                atomicAdd(&psum[b * EE + choff + orow + r], s);
                atomicMax(&pmax[b * EE + choff + orow + r], fmapu(m));
            }
        }
    }
}

__global__ __launch_bounds__(256, 2) void conv_all(
        const unsigned short* __restrict__ xh, const unsigned short* __restrict__ wrep,
        const float* __restrict__ b3, const float* __restrict__ b5, const float* __restrict__ b7,
        unsigned short* __restrict__ fused, float* __restrict__ psum, unsigned* __restrict__ pmax) {
    __shared__ short8 smem[SMEM_CHUNKS];
    int z = blockIdx.z;
    int br = z % 3;          // interleave branches across dispatch order for CU mixing
    int b = z / 3;
    int y0 = blockIdx.x * 4;
    const unsigned short* xb = xh + (size_t)b * (XH * XW * CIN);
    if (br == 0)
        conv_branch<7>(xb, (const short8*)(wrep + 34 * 16384), b7, fused, psum, pmax, b, y0, 256, smem);
    else if (br == 1)
        conv_branch<5>(xb, (const short8*)(wrep + 9 * 16384),  b5, fused, psum, pmax, b, y0, 128, smem);
    else
        conv_branch<3>(xb, (const short8*)(wrep + 0 * 16384),  b3, fused, psum, pmax, b, y0, 0, smem);
}

// ---------- P2: channel attention (W2·relu(a)+W2·relu(b) = W2·(relu(a)+relu(b))) ----------
__global__ void attn_kernel(const float* __restrict__ psum, const unsigned* __restrict__ pmax,
                            const float* __restrict__ ca_w1, const float* __restrict__ ca_w2,
                            float* __restrict__ attn) {
    int b = blockIdx.x;
    __shared__ float av[EE], mxv[EE], hsum[HID];
    int t = threadIdx.x;
    if (t < EE) {
        av[t] = psum[b * EE + t] * (1.0f / (float)NPIX);
        mxv[t] = funmap(pmax[b * EE + t]);
    }
    __syncthreads();
    if (t < HID) {
        float sa = 0.f, sm = 0.f;
        for (int c = 0; c < EE; ++c) {
            float w = ca_w1[t * EE + c];
            sa += w * av[c];
            sm += w * mxv[c];
        }
        hsum[t] = fmaxf(sa, 0.f) + fmaxf(sm, 0.f);
    }
    __syncthreads();
    if (t < EE) {
        float s = 0.f;
        for (int h = 0; h < HID; ++h) s += ca_w2[t * HID + h] * hsum[h];
        attn[b * EE + t] = 1.f / (1.f + __expf(-s));
    }
}

// ---------- P3: 1x1 fusion GEMM (attn folded into LDS-staged B) + fused LayerNorm ----------
// block: one b, 64 tokens, M=384. 4 waves split M (96 each), all 64 tokens.
#define BPITCH 392  // token pitch in LDS (chs)
__global__ __launch_bounds__(256, 2) void fuse_ln(
        const unsigned short* __restrict__ fused, const unsigned short* __restrict__ fwb,
        const float* __restrict__ attn,
        const float* __restrict__ fusion_b, const float* __restrict__ ln_g,
        const float* __restrict__ ln_b, float* __restrict__ out) {
    int b = blockIdx.y;
    int p0 = blockIdx.x * 64;
    int lane = threadIdx.x & 63, wv = threadIdx.x >> 6;
    int l16 = lane & 15, g4 = lane >> 4;

    __shared__ unsigned short sB[64 * BPITCH];
    __shared__ float sattn[EE];
    __shared__ float s_sum[4][64], s_sq[4][64], s_mean[64], s_rstd[64];

    for (int i = threadIdx.x; i < EE; i += 256) sattn[i] = attn[b * EE + i];
    __syncthreads();

    // stage 64 tokens x 384 ch, scaled by attn
    const unsigned short* fb = fused + ((size_t)(b * NPIX + p0)) * EE;
    for (int i = threadIdx.x; i < 64 * 48; i += 256) {
        int cg = i % 48, tok = i / 48;
        short8 raw = *(const short8*)(fb + tok * EE + cg * 8);
        short8 o;
        #pragma unroll
        for (int j = 0; j < 8; ++j)
            o[j] = (short)f2bf(bf2f((unsigned short)raw[j]) * sattn[cg * 8 + j]);
        *(short8*)(sB + tok * BPITCH + cg * 8) = o;
    }
    __syncthreads();

    f32x4 acc[6][4];
    #pragma unroll
    for (int i = 0; i < 6; ++i)
        #pragma unroll
        for (int j = 0; j < 4; ++j) acc[i][j] = (f32x4){0.f, 0.f, 0.f, 0.f};

    const short8* fw8 = (const short8*)fwb;
    for (int cb = 0; cb < 12; ++cb) {
        int c0 = cb * 32 + g4 * 8;
        short8 a[6];
        #pragma unroll
        for (int mt = 0; mt < 6; ++mt)
            a[mt] = fw8[(cb * 24 + wv * 6 + mt) * 64 + lane];  // lane-contiguous
        #pragma unroll
        for (int nt = 0; nt < 4; ++nt) {
            short8 bf = *(const short8*)(sB + (nt * 16 + l16) * BPITCH + c0);
            #pragma unroll
            for (int mt = 0; mt < 6; ++mt)
                acc[mt][nt] = __builtin_amdgcn_mfma_f32_16x16x32_bf16(a[mt], bf, acc[mt][nt], 0, 0, 0);
        }
    }

    // bias add + per-wave LN partials
    #pragma unroll
    for (int nt = 0; nt < 4; ++nt) {
        float ps = 0.f, pq = 0.f;
        #pragma unroll
        for (int mt = 0; mt < 6; ++mt) {
            int o = wv * 96 + mt * 16 + g4 * 4;
            f32x4 bv = *(const f32x4*)(fusion_b + o);
            #pragma unroll
            for (int r = 0; r < 4; ++r) {
                float v = acc[mt][nt][r] + bv[r];
                acc[mt][nt][r] = v;
                ps += v;
                pq += v * v;
            }
        }
        ps += __shfl_xor(ps, 16); pq += __shfl_xor(pq, 16);
        ps += __shfl_xor(ps, 32); pq += __shfl_xor(pq, 32);
        if (g4 == 0) { s_sum[wv][nt * 16 + l16] = ps; s_sq[wv][nt * 16 + l16] = pq; }
    }
    __syncthreads();
    if (threadIdx.x < 64) {
        int pix = threadIdx.x;
        float s = 0.f, q = 0.f;
        #pragma unroll
        for (int w = 0; w < 4; ++w) { s += s_sum[w][pix]; q += s_sq[w][pix]; }
        float mean = s * (1.0f / (float)EE);
        float var = q * (1.0f / (float)EE) - mean * mean;
        s_mean[pix] = mean;
        s_rstd[pix] = rsqrtf(var + 1e-5f);
    }
    __syncthreads();

    #pragma unroll
    for (int nt = 0; nt < 4; ++nt) {
        int pix = nt * 16 + l16;
        float mean = s_mean[pix], rstd = s_rstd[pix];
        size_t tokbase = ((size_t)(b * NPIX + p0 + pix)) * EE;
        #pragma unroll
        for (int mt = 0; mt < 6; ++mt) {
            int o = wv * 96 + mt * 16 + g4 * 4;
            f32x4 g = *(const f32x4*)(ln_g + o);
            f32x4 be = *(const f32x4*)(ln_b + o);
            f32x4 res;
            #pragma unroll
            for (int r = 0; r < 4; ++r)
                res[r] = (acc[mt][nt][r] - mean) * rstd * g[r] + be[r];
            *(f32x4*)(out + tokbase + o) = res;
        }
    }
}

// ---------- launch ----------
extern "C" void kernel_launch(void* const* d_in, const int* in_sizes, int n_in,
                              void* d_out, int out_size, void* d_ws, size_t ws_size,
                              hipStream_t stream) {
    const float* x    = (const float*)d_in[0];
    const float* w3   = (const float*)d_in[1];
    const float* b3   = (const float*)d_in[2];
    const float* w5   = (const float*)d_in[3];
    const float* b5   = (const float*)d_in[4];
    const float* w7   = (const float*)d_in[5];
    const float* b7   = (const float*)d_in[6];
    const float* caw1 = (const float*)d_in[7];
    const float* caw2 = (const float*)d_in[8];
    const float* fw   = (const float*)d_in[9];
    const float* fbias= (const float*)d_in[10];
    const float* lng  = (const float*)d_in[11];
    const float* lnb  = (const float*)d_in[12];
    float* out = (float*)d_out;

    char* ws = (char*)d_ws;
    size_t off = 0;
    unsigned short* xh   = (unsigned short*)(ws + off); off += (size_t)BB * XH * XW * CIN * 2;       // 41.3 MB
    unsigned short* wrep = (unsigned short*)(ws + off); off += (size_t)83 * EBC * CIN * 2;           // 2.7 MB
    unsigned short* fwb  = (unsigned short*)(ws + off); off += (size_t)EE * EE * 2;                  // 0.3 MB
    unsigned short* fused= (unsigned short*)(ws + off); off += (size_t)NTOK * EE * 2;                // 100.7 MB
    float*    psum = (float*)(ws + off);    off += (size_t)BB * EE * 4;
    unsigned* pmax = (unsigned*)(ws + off); off += (size_t)BB * EE * 4;
    float*    attn = (float*)(ws + off);    off += (size_t)BB * EE * 4;

    repack_x<<<dim3(XH, BB), 256, 0, stream>>>(x, xh);
    repack_w<<<dim3(5312), 256, 0, stream>>>(w3, w5, w7, fw, wrep, fwb, psum, pmax);

    conv_all<<<dim3(16, 1, 3 * BB), 256, 0, stream>>>(xh, wrep, b3, b5, b7, fused, psum, pmax);

    attn_kernel<<<dim3(BB), 384, 0, stream>>>(psum, pmax, caw1, caw2, attn);
    fuse_ln<<<dim3(NPIX / 64, BB), 256, 0, stream>>>(fused, fwb, attn, fbias, lng, lnb, out);
}

// Round 3
// 647.715 us; speedup vs baseline: 1.1004x; 1.0641x over previous
//
#include <hip/hip_runtime.h>

// ---------- shapes ----------
#define BB 32
#define CIN 128
#define HH 64
#define WW 64
#define EE 384
#define EBC 128   // per-branch channels
#define HID 24
#define NPIX (HH*WW)          // 4096
#define NTOK (BB*NPIX)        // 131072

// padded bf16 input: [B][XH][XW][CIN], zero halo (rows +3 top, cols +3 left)
#define XW 70
#define XH 72

typedef __attribute__((ext_vector_type(8))) short short8;
typedef __attribute__((ext_vector_type(4))) float f32x4;
typedef __attribute__((ext_vector_type(4))) unsigned short us4;

__device__ __forceinline__ unsigned short f2bf(float f) {
    unsigned u = __float_as_uint(f);
    unsigned r = u + 0x7fffu + ((u >> 16) & 1u);
    return (unsigned short)(r >> 16);
}
__device__ __forceinline__ float bf2f(unsigned short u) {
    return __uint_as_float(((unsigned)u) << 16);
}
// monotone float -> uint mapping for atomicMax over signed floats
__device__ __forceinline__ unsigned fmapu(float f) {
    unsigned u = __float_as_uint(f);
    return (u & 0x80000000u) ? ~u : (u | 0x80000000u);
}
__device__ __forceinline__ float funmap(unsigned u) {
    unsigned b = (u & 0x80000000u) ? (u ^ 0x80000000u) : ~u;
    return __uint_as_float(b);
}

// ---------- P0a: x [B,C,H,W] f32 -> xh [B,XH,XW,C] bf16 padded, zero halo ----------
__global__ void repack_x(const float* __restrict__ x, unsigned short* __restrict__ xh) {
    int py = blockIdx.x, b = blockIdx.y;
    int y = py - 3;
    unsigned short* orow = xh + ((size_t)(b * XH + py)) * XW * CIN;
    if ((unsigned)y >= (unsigned)HH) {
        // zero row: 70*128 shorts = 1120 short8 chunks
        for (int i = threadIdx.x; i < XW * CIN / 8; i += 256)
            ((short8*)orow)[i] = (short8){};
        return;
    }
    __shared__ unsigned short t[CIN][WW + 6];
    const float* xp = x + (((size_t)b * CIN) * HH + y) * WW;
    #pragma unroll
    for (int it = 0; it < 32; ++it) {
        int xc = threadIdx.x & 63;
        int c = (threadIdx.x >> 6) + it * 4;
        t[c][xc] = f2bf(xp[(size_t)c * NPIX + xc]);
    }
    __syncthreads();
    unsigned short* op = orow + 3 * CIN;  // interior starts at px=3
    #pragma unroll
    for (int it = 0; it < 8; ++it) {
        int id = threadIdx.x + it * 256;
        int xc = id >> 5, c0 = (id & 31) * 4;
        us4 v = { t[c0][xc], t[c0 + 1][xc], t[c0 + 2][xc], t[c0 + 3][xc] };
        *(us4*)(op + xc * CIN + c0) = v;
    }
    // zero left/right halos: px {0,1,2,67,68,69}, 16 chunks each
    if (threadIdx.x < 96) {
        int pxsel = threadIdx.x >> 4;                // 0..5
        int px = pxsel < 3 ? pxsel : 64 + pxsel;     // 0,1,2,67,68,69
        ((short8*)(orow + px * CIN))[threadIdx.x & 15] = (short8){};
    }
}

// ---------- P0b: conv weights -> fragment-ordered bf16 [tap][cb][mt][lane][8ch],
//            fusion_w -> fragment-ordered bf16 [cb12][m24][lane][8ch], init pools ----------
__global__ void repack_w(const float* __restrict__ w3, const float* __restrict__ w5,
                         const float* __restrict__ w7, const float* __restrict__ fw,
                         unsigned short* __restrict__ wrep, unsigned short* __restrict__ fwb,
                         float* __restrict__ psum, unsigned* __restrict__ pmax) {
    int idx = blockIdx.x * 256 + threadIdx.x;
    if (idx < 83 * 16384) {
        int j = idx & 7;
        int lane = (idx >> 3) & 63;
        int mt = (idx >> 9) & 7;
        int cb = (idx >> 12) & 3;
        int t = idx >> 14;
        int l16 = lane & 15, g4 = lane >> 4;
        int o = mt * 16 + l16;
        int c = cb * 32 + g4 * 8 + j;
        float v;
        if (t < 9)       { int tt = t;      int dy = tt / 3, dx = tt % 3; v = w3[((o * CIN + c) * 3 + dy) * 3 + dx]; }
        else if (t < 34) { int tt = t - 9;  int dy = tt / 5, dx = tt % 5; v = w5[((o * CIN + c) * 5 + dy) * 5 + dx]; }
        else             { int tt = t - 34; int dy = tt / 7, dx = tt % 7; v = w7[((o * CIN + c) * 7 + dy) * 7 + dx]; }
        wrep[idx] = f2bf(v);
    }
    if (idx < EE * EE) {
        int j = idx & 7;
        int lane = (idx >> 3) & 63;
        int mc = idx >> 9;           // 0..287 = cb*24 + m
        int m = mc % 24, cb = mc / 24;
        int l16 = lane & 15, g4 = lane >> 4;
        int o = m * 16 + l16;
        int c = cb * 32 + g4 * 8 + j;
        fwb[idx] = f2bf(fw[o * EE + c]);
    }
    if (idx < BB * EE) { psum[idx] = 0.f; pmax[idx] = 0u; }
}

// ---------- P1: all three convs in ONE kernel (implicit GEMM, async-staged LDS tile) ----------
// block: (y-tile of 4 rows, branch x batch). 4 waves.
// Wave decomposition = (M-half x row-pair): each wave computes 64 out-ch x 2 rows (128 px).
// This halves the per-block redundant A (weight) traffic from L2 vs all-waves-read-all-M:
// A = 16KB/tap/block instead of 32KB -> ~26 B/cyc/CU demand, under the ~56 B/cyc L2 ceiling.
// Staging via global_load_lds (async, zero VALU bounds checks thanks to padded xh).

#define SMEM_CHUNKS 2832   // KS=7: 10*4*70 = 2800 chunks + 32 pad for partial instr overflow

template <int KS>
__device__ __forceinline__ void conv_branch(
        const unsigned short* __restrict__ xb,     // batch base of padded xh
        const short8* __restrict__ wv8,            // fragment-ordered weights for this branch
        const float* __restrict__ bias, unsigned short* __restrict__ fused,
        float* __restrict__ psum, unsigned* __restrict__ pmax,
        int b, int y0, int choff, short8* smem) {
    constexpr int PK = KS / 2;
    constexpr int RT = 4 + 2 * PK;          // tile rows
    constexpr int TPX = 64 + 2 * PK;        // tile px (with halo)
    constexpr int NCH = RT * 4 * TPX;       // 16B chunks in tile
    constexpr int NT = KS * KS;             // taps
    constexpr int NINSTR = (NCH + 63) / 64; // global_load_lds per cb

    int lane = threadIdx.x & 63, wv = threadIdx.x >> 6;
    int l16 = lane & 15, g4 = lane >> 4;
    int mh = wv >> 1;          // M-half (64 out-ch)
    int rbase = (wv & 1) * 2;  // row-pair base within the 4-row tile

    f32x4 acc[4][8];
    #pragma unroll
    for (int i = 0; i < 4; ++i)
        #pragma unroll
        for (int j = 0; j < 8; ++j) acc[i][j] = (f32x4){0.f, 0.f, 0.f, 0.f};

    for (int cb = 0; cb < 4; ++cb) {
        if (cb) __syncthreads();
        // async stage: each wave issues NINSTR/4 global_load_lds of 1KB each.
        // LDS chunk c = k*64+lane maps to (r,g,p); global src is per-lane.
        for (int k = wv; k < NINSTR; k += 4) {
            int c = k * 64 + lane;
            int rg = c / TPX;
            int p = c - rg * TPX;
            int r = rg >> 2;
            int g = rg & 3;
            const unsigned short* src = xb +
                ((size_t)((y0 + r - PK + 3) * XW + (p - PK + 3))) * CIN + cb * 32 + g * 8;
            short8* dst = smem + k * 64;   // wave-uniform base; HW adds lane*16
            __builtin_amdgcn_global_load_lds(
                (const __attribute__((address_space(1))) void*)src,
                (__attribute__((address_space(3))) void*)dst, 16, 0, 0);
        }
        // preload A for tap 0 (completes during staging drain)
        short8 a0[4], a1[4];
        {
            const short8* wf = wv8 + ((size_t)(cb * 8 + mh * 4)) * 64 + lane;
            #pragma unroll
            for (int mt = 0; mt < 4; ++mt) a0[mt] = wf[mt * 64];
        }
        __syncthreads();

        #pragma unroll
        for (int t = 0; t < NT; ++t) {
            short8* ac = (t & 1) ? a1 : a0;   // static under full unroll
            short8* an = (t & 1) ? a0 : a1;
            int dy = t / KS, dx = t % KS;
            short8 bfv[8];
            #pragma unroll
            for (int rsel = 0; rsel < 2; ++rsel)
                #pragma unroll
                for (int ct = 0; ct < 4; ++ct)
                    bfv[rsel * 4 + ct] =
                        smem[((rbase + rsel + dy) * 4 + g4) * TPX + l16 + dx + ct * 16];
            if (t + 1 < NT) {
                const short8* wf = wv8 + ((size_t)(((t + 1) * 4 + cb) * 8 + mh * 4)) * 64 + lane;
                #pragma unroll
                for (int mt = 0; mt < 4; ++mt) an[mt] = wf[mt * 64];
            }
            // pin: all loads above must issue before the MFMA cluster below
            __builtin_amdgcn_sched_barrier(0);
            #pragma unroll
            for (int nt = 0; nt < 8; ++nt)
                #pragma unroll
                for (int mt = 0; mt < 4; ++mt)
                    acc[mt][nt] = __builtin_amdgcn_mfma_f32_16x16x32_bf16(ac[mt], bfv[nt], acc[mt][nt], 0, 0, 0);
        }
    }

    // epilogue: bias, bf16 store (token layout), channel pooling
    #pragma unroll
    for (int mt = 0; mt < 4; ++mt) {
        int orow = mh * 64 + mt * 16 + g4 * 4;  // C/D: row = g4*4 + reg
        f32x4 bv = *(const f32x4*)(bias + orow);
        float sacc[4] = {0.f, 0.f, 0.f, 0.f};
        float macc[4] = {-1e30f, -1e30f, -1e30f, -1e30f};
        #pragma unroll
        for (int nt = 0; nt < 8; ++nt) {
            int rsel = nt >> 2, ct = nt & 3;
            int y = y0 + rbase + rsel;
            int pix = y * WW + ct * 16 + l16;  // col = lane&15
            us4 pk;
            #pragma unroll
            for (int r = 0; r < 4; ++r) {
                float vv = acc[mt][nt][r] + bv[r];
                sacc[r] += vv;
                macc[r] = fmaxf(macc[r], vv);
                pk[r] = f2bf(vv);
            }
            *(us4*)(fused + ((size_t)(b * NPIX + pix)) * EE + choff + orow) = pk;
        }
        #pragma unroll
        for (int r = 0; r < 4; ++r) {
            float s = sacc[r], m = macc[r];
            #pragma unroll
            for (int sh = 1; sh < 16; sh <<= 1) {
                s += __shfl_xor(s, sh);
                m = fmaxf(m, __shfl_xor(m, sh));
            }
            if (l16 == 0) {
                atomicAdd(&psum[b * EE + choff + orow + r], s);
                atomicMax(&pmax[b * EE + choff + orow + r], fmapu(m));
            }
        }
    }
}

__global__ __launch_bounds__(256, 2) void conv_all(
        const unsigned short* __restrict__ xh, const unsigned short* __restrict__ wrep,
        const float* __restrict__ b3, const float* __restrict__ b5, const float* __restrict__ b7,
        unsigned short* __restrict__ fused, float* __restrict__ psum, unsigned* __restrict__ pmax) {
    __shared__ short8 smem[SMEM_CHUNKS];
    int z = blockIdx.z;
    int br = z % 3;          // interleave branches across dispatch order for CU mixing
    int b = z / 3;
    int y0 = blockIdx.x * 4;
    const unsigned short* xb = xh + (size_t)b * (XH * XW * CIN);
    if (br == 0)
        conv_branch<7>(xb, (const short8*)(wrep + 34 * 16384), b7, fused, psum, pmax, b, y0, 256, smem);
    else if (br == 1)
        conv_branch<5>(xb, (const short8*)(wrep + 9 * 16384),  b5, fused, psum, pmax, b, y0, 128, smem);
    else
        conv_branch<3>(xb, (const short8*)(wrep + 0 * 16384),  b3, fused, psum, pmax, b, y0, 0, smem);
}

// ---------- P2: channel attention (W2·relu(a)+W2·relu(b) = W2·(relu(a)+relu(b))) ----------
__global__ void attn_kernel(const float* __restrict__ psum, const unsigned* __restrict__ pmax,
                            const float* __restrict__ ca_w1, const float* __restrict__ ca_w2,
                            float* __restrict__ attn) {
    int b = blockIdx.x;
    __shared__ float av[EE], mxv[EE], hsum[HID];
    int t = threadIdx.x;
    if (t < EE) {
        av[t] = psum[b * EE + t] * (1.0f / (float)NPIX);
        mxv[t] = funmap(pmax[b * EE + t]);
    }
    __syncthreads();
    if (t < HID) {
        float sa = 0.f, sm = 0.f;
        for (int c = 0; c < EE; ++c) {
            float w = ca_w1[t * EE + c];
            sa += w * av[c];
            sm += w * mxv[c];
        }
        hsum[t] = fmaxf(sa, 0.f) + fmaxf(sm, 0.f);
    }
    __syncthreads();
    if (t < EE) {
        float s = 0.f;
        for (int h = 0; h < HID; ++h) s += ca_w2[t * HID + h] * hsum[h];
        attn[b * EE + t] = 1.f / (1.f + __expf(-s));
    }
}

// ---------- P3: 1x1 fusion GEMM (attn folded into LDS-staged B) + fused LayerNorm ----------
// block: one b, 64 tokens, M=384. 4 waves split M (96 each), all 64 tokens.
#define BPITCH 392  // token pitch in LDS (chs)
__global__ __launch_bounds__(256, 2) void fuse_ln(
        const unsigned short* __restrict__ fused, const unsigned short* __restrict__ fwb,
        const float* __restrict__ attn,
        const float* __restrict__ fusion_b, const float* __restrict__ ln_g,
        const float* __restrict__ ln_b, float* __restrict__ out) {
    int b = blockIdx.y;
    int p0 = blockIdx.x * 64;
    int lane = threadIdx.x & 63, wv = threadIdx.x >> 6;
    int l16 = lane & 15, g4 = lane >> 4;

    __shared__ unsigned short sB[64 * BPITCH];
    __shared__ float sattn[EE];
    __shared__ float s_sum[4][64], s_sq[4][64], s_mean[64], s_rstd[64];

    for (int i = threadIdx.x; i < EE; i += 256) sattn[i] = attn[b * EE + i];
    __syncthreads();

    // stage 64 tokens x 384 ch, scaled by attn
    const unsigned short* fb = fused + ((size_t)(b * NPIX + p0)) * EE;
    for (int i = threadIdx.x; i < 64 * 48; i += 256) {
        int cg = i % 48, tok = i / 48;
        short8 raw = *(const short8*)(fb + tok * EE + cg * 8);
        short8 o;
        #pragma unroll
        for (int j = 0; j < 8; ++j)
            o[j] = (short)f2bf(bf2f((unsigned short)raw[j]) * sattn[cg * 8 + j]);
        *(short8*)(sB + tok * BPITCH + cg * 8) = o;
    }
    __syncthreads();

    f32x4 acc[6][4];
    #pragma unroll
    for (int i = 0; i < 6; ++i)
        #pragma unroll
        for (int j = 0; j < 4; ++j) acc[i][j] = (f32x4){0.f, 0.f, 0.f, 0.f};

    const short8* fw8 = (const short8*)fwb;
    for (int cb = 0; cb < 12; ++cb) {
        int c0 = cb * 32 + g4 * 8;
        short8 a[6];
        #pragma unroll
        for (int mt = 0; mt < 6; ++mt)
            a[mt] = fw8[(cb * 24 + wv * 6 + mt) * 64 + lane];  // lane-contiguous
        #pragma unroll
        for (int nt = 0; nt < 4; ++nt) {
            short8 bf = *(const short8*)(sB + (nt * 16 + l16) * BPITCH + c0);
            #pragma unroll
            for (int mt = 0; mt < 6; ++mt)
                acc[mt][nt] = __builtin_amdgcn_mfma_f32_16x16x32_bf16(a[mt], bf, acc[mt][nt], 0, 0, 0);
        }
    }

    // bias add + per-wave LN partials
    #pragma unroll
    for (int nt = 0; nt < 4; ++nt) {
        float ps = 0.f, pq = 0.f;
        #pragma unroll
        for (int mt = 0; mt < 6; ++mt) {
            int o = wv * 96 + mt * 16 + g4 * 4;
            f32x4 bv = *(const f32x4*)(fusion_b + o);
            #pragma unroll
            for (int r = 0; r < 4; ++r) {
                float v = acc[mt][nt][r] + bv[r];
                acc[mt][nt][r] = v;
                ps += v;
                pq += v * v;
            }
        }
        ps += __shfl_xor(ps, 16); pq += __shfl_xor(pq, 16);
        ps += __shfl_xor(ps, 32); pq += __shfl_xor(pq, 32);
        if (g4 == 0) { s_sum[wv][nt * 16 + l16] = ps; s_sq[wv][nt * 16 + l16] = pq; }
    }
    __syncthreads();
    if (threadIdx.x < 64) {
        int pix = threadIdx.x;
        float s = 0.f, q = 0.f;
        #pragma unroll
        for (int w = 0; w < 4; ++w) { s += s_sum[w][pix]; q += s_sq[w][pix]; }
        float mean = s * (1.0f / (float)EE);
        float var = q * (1.0f / (float)EE) - mean * mean;
        s_mean[pix] = mean;
        s_rstd[pix] = rsqrtf(var + 1e-5f);
    }
    __syncthreads();

    #pragma unroll
    for (int nt = 0; nt < 4; ++nt) {
        int pix = nt * 16 + l16;
        float mean = s_mean[pix], rstd = s_rstd[pix];
        size_t tokbase = ((size_t)(b * NPIX + p0 + pix)) * EE;
        #pragma unroll
        for (int mt = 0; mt < 6; ++mt) {
            int o = wv * 96 + mt * 16 + g4 * 4;
            f32x4 g = *(const f32x4*)(ln_g + o);
            f32x4 be = *(const f32x4*)(ln_b + o);
            f32x4 res;
            #pragma unroll
            for (int r = 0; r < 4; ++r)
                res[r] = (acc[mt][nt][r] - mean) * rstd * g[r] + be[r];
            *(f32x4*)(out + tokbase + o) = res;
        }
    }
}

// ---------- launch ----------
extern "C" void kernel_launch(void* const* d_in, const int* in_sizes, int n_in,
                              void* d_out, int out_size, void* d_ws, size_t ws_size,
                              hipStream_t stream) {
    const float* x    = (const float*)d_in[0];
    const float* w3   = (const float*)d_in[1];
    const float* b3   = (const float*)d_in[2];
    const float* w5   = (const float*)d_in[3];
    const float* b5   = (const float*)d_in[4];
    const float* w7   = (const float*)d_in[5];
    const float* b7   = (const float*)d_in[6];
    const float* caw1 = (const float*)d_in[7];
    const float* caw2 = (const float*)d_in[8];
    const float* fw   = (const float*)d_in[9];
    const float* fbias= (const float*)d_in[10];
    const float* lng  = (const float*)d_in[11];
    const float* lnb  = (const float*)d_in[12];
    float* out = (float*)d_out;

    char* ws = (char*)d_ws;
    size_t off = 0;
    unsigned short* xh   = (unsigned short*)(ws + off); off += (size_t)BB * XH * XW * CIN * 2;       // 41.3 MB
    unsigned short* wrep = (unsigned short*)(ws + off); off += (size_t)83 * EBC * CIN * 2;           // 2.7 MB
    unsigned short* fwb  = (unsigned short*)(ws + off); off += (size_t)EE * EE * 2;                  // 0.3 MB
    unsigned short* fused= (unsigned short*)(ws + off); off += (size_t)NTOK * EE * 2;                // 100.7 MB
    float*    psum = (float*)(ws + off);    off += (size_t)BB * EE * 4;
    unsigned* pmax = (unsigned*)(ws + off); off += (size_t)BB * EE * 4;
    float*    attn = (float*)(ws + off);    off += (size_t)BB * EE * 4;

    repack_x<<<dim3(XH, BB), 256, 0, stream>>>(x, xh);
    repack_w<<<dim3(5312), 256, 0, stream>>>(w3, w5, w7, fw, wrep, fwb, psum, pmax);

    conv_all<<<dim3(16, 1, 3 * BB), 256, 0, stream>>>(xh, wrep, b3, b5, b7, fused, psum, pmax);

    attn_kernel<<<dim3(BB), 384, 0, stream>>>(psum, pmax, caw1, caw2, attn);
    fuse_ln<<<dim3(NPIX / 64, BB), 256, 0, stream>>>(fused, fwb, attn, fbias, lng, lnb, out);
}